// Round 5
// baseline (50.426 us; speedup 1.0000x reference)
//
#include <hip/hip_runtime.h>
#include <math.h>

// WindingEmbedding, fully fused single kernel (occupancy-tuned).
// rows = 32768 (B=8, S=4096), D=1024, W=8 windings, F=16 feats.
// out[row][d] = ((emb - mu) * rsqrt(var+eps)) * gamma + beta
// emb[row][d] = sum_f feats[row][f] * pw[d][f] + pb[d]
//
// Block = 256 threads, 16 rows/block, processed in 4 chunks of 4 rows to cap
// VGPR liveness (er[4][4]); __launch_bounds__(256,4) forces <=128 VGPR ->
// 4 waves/SIMD. Stats via 6-step __shfl_xor + parity-double-buffered LDS
// combine (one __syncthreads per chunk). Output via nontemporal float4 stores
// (native ext_vector_type — __builtin_nontemporal_store rejects HIP_vector_type).

#define TWO_PI 6.28318530717958647692f
#define INV_VOCAB (1.0f / 50257.0f)
#define INV_D (1.0f / 1024.0f)

typedef float f32x4 __attribute__((ext_vector_type(4)));

__global__ __launch_bounds__(256, 4) void wind_fused(const int* __restrict__ x,
                                                     const float* __restrict__ winds,
                                                     const float* __restrict__ pw,
                                                     const float* __restrict__ pb,
                                                     const float* __restrict__ gamma,
                                                     const float* __restrict__ beta,
                                                     float* __restrict__ out) {
  __shared__ __align__(16) float feat[16][16];  // 16 rows x 16 feats (reads are broadcast)
  __shared__ float red[2][4][4][2];             // [chunk parity][wave][rowInChunk][sum|sumsq]

  const int tid = threadIdx.x;
  const int wave = tid >> 6;
  const int lane = tid & 63;
  const int base = blockIdx.x * 16;
  const int d0 = tid << 2;  // this thread's 4 output dims

  // Register-cache projection rows for dims d0..d0+3 (64 floats) + bias.
  float4 wreg[4][4];
#pragma unroll
  for (int r = 0; r < 4; ++r)
#pragma unroll
    for (int c = 0; c < 4; ++c)
      wreg[r][c] = reinterpret_cast<const float4*>(pw)[(d0 + r) * 4 + c];
  const float4 pbv = reinterpret_cast<const float4*>(pb)[tid];

  // ---- Stage the 16x16 feature tile: one sincos per thread ----
  {
    const int rl = tid >> 4;  // row 0..15
    const int j = tid & 15;   // feature index
    const float tf = (float)x[base + rl] * INV_VOCAB;
    float s, c;
    sincosf(TWO_PI * tf * winds[j >> 1], &s, &c);
    feat[rl][j] = (j & 1) ? s : c;  // interleaved [cos0,sin0,cos1,sin1,...]
  }
  __syncthreads();

  const float4 gv = reinterpret_cast<const float4*>(gamma)[tid];
  const float4 bv = reinterpret_cast<const float4*>(beta)[tid];

  // ---- 4 chunks of 4 rows each ----
#pragma unroll
  for (int h = 0; h < 4; ++h) {
    float er[4][4];
    float sr[4], qr[4];

#pragma unroll
    for (int r = 0; r < 4; ++r) {
      const int rr = h * 4 + r;
      const float4 F0 = *reinterpret_cast<const float4*>(&feat[rr][0]);
      const float4 F1 = *reinterpret_cast<const float4*>(&feat[rr][4]);
      const float4 F2 = *reinterpret_cast<const float4*>(&feat[rr][8]);
      const float4 F3 = *reinterpret_cast<const float4*>(&feat[rr][12]);
#pragma unroll
      for (int k = 0; k < 4; ++k) {
        float a = (k == 0) ? pbv.x : (k == 1) ? pbv.y : (k == 2) ? pbv.z : pbv.w;
        a = fmaf(wreg[k][0].x, F0.x, a);
        a = fmaf(wreg[k][0].y, F0.y, a);
        a = fmaf(wreg[k][0].z, F0.z, a);
        a = fmaf(wreg[k][0].w, F0.w, a);
        a = fmaf(wreg[k][1].x, F1.x, a);
        a = fmaf(wreg[k][1].y, F1.y, a);
        a = fmaf(wreg[k][1].z, F1.z, a);
        a = fmaf(wreg[k][1].w, F1.w, a);
        a = fmaf(wreg[k][2].x, F2.x, a);
        a = fmaf(wreg[k][2].y, F2.y, a);
        a = fmaf(wreg[k][2].z, F2.z, a);
        a = fmaf(wreg[k][2].w, F2.w, a);
        a = fmaf(wreg[k][3].x, F3.x, a);
        a = fmaf(wreg[k][3].y, F3.y, a);
        a = fmaf(wreg[k][3].z, F3.z, a);
        a = fmaf(wreg[k][3].w, F3.w, a);
        er[r][k] = a;
      }
      sr[r] = (er[r][0] + er[r][1]) + (er[r][2] + er[r][3]);
      float q = er[r][0] * er[r][0];
      q = fmaf(er[r][1], er[r][1], q);
      q = fmaf(er[r][2], er[r][2], q);
      q = fmaf(er[r][3], er[r][3], q);
      qr[r] = q;
    }

    // Wave-level butterfly reduce (64 lanes), 4 independent rows for ILP.
#pragma unroll
    for (int r = 0; r < 4; ++r) {
#pragma unroll
      for (int off = 1; off < 64; off <<= 1) {
        sr[r] += __shfl_xor(sr[r], off);
        qr[r] += __shfl_xor(qr[r], off);
      }
    }
    if (lane == 0) {
#pragma unroll
      for (int r = 0; r < 4; ++r) {
        red[h & 1][wave][r][0] = sr[r];
        red[h & 1][wave][r][1] = qr[r];
      }
    }
    __syncthreads();  // orders this chunk's red writes before its reads;
                      // also fences the next reuse of this parity buffer.

    // Finalize + coalesced nontemporal store (broadcast LDS reads).
    float* o = out + (size_t)(base + h * 4) * 1024 + d0;
#pragma unroll
    for (int r = 0; r < 4; ++r) {
      const float s = (red[h & 1][0][r][0] + red[h & 1][1][r][0]) +
                      (red[h & 1][2][r][0] + red[h & 1][3][r][0]);
      const float q = (red[h & 1][0][r][1] + red[h & 1][1][r][1]) +
                      (red[h & 1][2][r][1] + red[h & 1][3][r][1]);
      const float mu = s * INV_D;
      const float var = fmaf(q, INV_D, -mu * mu);
      const float rs = rsqrtf(var + 1e-5f);
      const float s0 = gv.x * rs, s1 = gv.y * rs, s2 = gv.z * rs, s3 = gv.w * rs;
      f32x4 res;
      res.x = fmaf(er[r][0], s0, fmaf(-mu, s0, bv.x));
      res.y = fmaf(er[r][1], s1, fmaf(-mu, s1, bv.y));
      res.z = fmaf(er[r][2], s2, fmaf(-mu, s2, bv.z));
      res.w = fmaf(er[r][3], s3, fmaf(-mu, s3, bv.w));
      __builtin_nontemporal_store(res, reinterpret_cast<f32x4*>(o + (size_t)r * 1024));
    }
  }
}

extern "C" void kernel_launch(void* const* d_in, const int* in_sizes, int n_in,
                              void* d_out, int out_size, void* d_ws, size_t ws_size,
                              hipStream_t stream) {
  const int* x = (const int*)d_in[0];
  const float* winds = (const float*)d_in[1];
  const float* pw = (const float*)d_in[2];
  const float* pb = (const float*)d_in[3];
  const float* gamma = (const float*)d_in[4];
  const float* beta = (const float*)d_in[5];
  float* out = (float*)d_out;

  const int rows = in_sizes[0];  // 32768
  wind_fused<<<rows / 16, 256, 0, stream>>>(x, winds, pw, pb, gamma, beta, out);
}